// Round 15
// baseline (220.380 us; speedup 1.0000x reference)
//
#include <hip/hip_runtime.h>
#include <hip/hip_bf16.h>

typedef short bf16x8 __attribute__((ext_vector_type(8)));
typedef float f32x4 __attribute__((ext_vector_type(4)));
typedef float f32x16 __attribute__((ext_vector_type(16)));
typedef unsigned u32x2 __attribute__((ext_vector_type(2)));

#define N_B 4
#define N_T 2048
#define N_D 1024
#define N_H 16
#define N_DH 64
#define N_ROWS (N_B * N_H * N_T)   // 131072 (b,h,t) rows

// 0.125 * log2(e): folds attention scale + exp->exp2 conversion into Q proj
#define Q_SCALE 0.18033688011112042f

__device__ __forceinline__ unsigned short f2bf(float f) {
  union { float f; unsigned int u; } c; c.f = f;
  unsigned int u = c.u;
  return (unsigned short)((u + 0x7FFFu + ((u >> 16) & 1u)) >> 16);
}

__device__ __forceinline__ unsigned cvtpk_bf16(float lo, float hi) {
  unsigned r;
  asm("v_cvt_pk_bf16_f32 %0, %1, %2" : "=v"(r) : "v"(lo), "v"(hi));
  return r;
}

// async global->LDS, 16B per lane (dest linear: wave base + lane*16)
__device__ __forceinline__ void gll16(const unsigned short* g, unsigned short* l) {
  __builtin_amdgcn_global_load_lds(
      (const __attribute__((address_space(1))) unsigned int*)(const void*)g,
      (__attribute__((address_space(3))) unsigned int*)(void*)l, 16, 0, 0);
}

// --------------------------------------------------- cast fp32 -> bf16 (7 arrays)
__global__ void cast_all(const float* __restrict__ wq, const float* __restrict__ wk,
                         const float* __restrict__ wv, const float* __restrict__ wo,
                         const float* __restrict__ q, const float* __restrict__ k,
                         const float* __restrict__ v,
                         unsigned short* __restrict__ ws) {
  const int z = blockIdx.z;
  const float* srcs[7] = {wq, wk, wv, wo, q, k, v};
  const int size = (z < 4) ? (N_D * N_D) : (N_B * N_T * N_D);
  const size_t off = (z < 4) ? (size_t)z * (N_D * N_D)
                             : (size_t)4 * (N_D * N_D) + (size_t)(z - 4) * (N_B * N_T * N_D);
  const int i = (blockIdx.x * 256 + threadIdx.x) * 8;
  if (i >= size) return;
  const float* src = srcs[z];
  float4 a = *(const float4*)(src + i);
  float4 b = *(const float4*)(src + i + 4);
  bf16x8 p;
  p[0] = (short)f2bf(a.x); p[1] = (short)f2bf(a.y);
  p[2] = (short)f2bf(a.z); p[3] = (short)f2bf(a.w);
  p[4] = (short)f2bf(b.x); p[5] = (short)f2bf(b.y);
  p[6] = (short)f2bf(b.z); p[7] = (short)f2bf(b.w);
  *(bf16x8*)(ws + off + i) = p;
}

// --------------------------------------------------------- qkv projection GEMM
__launch_bounds__(256, 2)
__global__ void proj_qkv(const unsigned short* __restrict__ qb,
                         const unsigned short* __restrict__ kb,
                         const unsigned short* __restrict__ vb,
                         const unsigned short* __restrict__ wq,
                         const unsigned short* __restrict__ wk,
                         const unsigned short* __restrict__ wv,
                         unsigned short* __restrict__ qh,
                         unsigned short* __restrict__ kh,
                         unsigned short* __restrict__ vt) {
  const int z = blockIdx.z;
  const unsigned short* X = (z == 0) ? qb : (z == 1) ? kb : vb;
  const unsigned short* W = (z == 0) ? wq : (z == 1) ? wk : wv;
  unsigned short* O = (z == 0) ? qh : (z == 1) ? kh : vt;

  __shared__ unsigned short lds_a[128 * 64];
  __shared__ unsigned short lds_b[128 * 64];

  const int tid = threadIdx.x;
  const int wave = tid >> 6, lane = tid & 63;
  const int wm = wave >> 1, wn = wave & 1;
  const int lr = lane & 15, lg = lane >> 4;
  const int orig = blockIdx.y * 8 + blockIdx.x;
  const int swz = (orig & 7) * 64 + (orig >> 3);
  const int m0 = (swz >> 3) * 128, n0 = (swz & 7) * 128;
  const int sw = (lr & 7) << 4;

  f32x4 acc[4][4] = {};

  for (int k0 = 0; k0 < N_D; k0 += 64) {
    __syncthreads();
#pragma unroll
    for (int it = 0; it < 4; ++it) {
      int c = it * 256 + tid;
      int row = c >> 3;
      int sb = ((c & 7) * 16) ^ ((row & 7) << 4);
      gll16(&X[(size_t)(m0 + row) * N_D + k0 + (sb >> 1)], &lds_a[c * 8]);
      gll16(&W[(size_t)(n0 + row) * N_D + k0 + (sb >> 1)], &lds_b[c * 8]);
    }
    __syncthreads();

#pragma unroll
    for (int kk = 0; kk < 2; ++kk) {
      bf16x8 af[4], bfr[4];
      const int cb = (lg * 16 + kk * 64);
#pragma unroll
      for (int m = 0; m < 4; ++m)
        af[m] = *(bf16x8*)&lds_a[(wm * 64 + m * 16 + lr) * 64 + ((cb ^ sw) >> 1)];
#pragma unroll
      for (int n = 0; n < 4; ++n)
        bfr[n] = *(bf16x8*)&lds_b[(wn * 64 + n * 16 + lr) * 64 + ((cb ^ sw) >> 1)];
#pragma unroll
      for (int m = 0; m < 4; ++m)
#pragma unroll
        for (int n = 0; n < 4; ++n)
          acc[m][n] = __builtin_amdgcn_mfma_f32_16x16x32_bf16(af[m], bfr[n], acc[m][n], 0, 0, 0);
    }
  }

  const float osc = (z == 0) ? Q_SCALE : 1.0f;
#pragma unroll
  for (int m = 0; m < 4; ++m)
#pragma unroll
    for (int n = 0; n < 4; ++n)
#pragma unroll
      for (int r = 0; r < 4; ++r) {
        int row = m0 + wm * 64 + m * 16 + lg * 4 + r;   // token (b*T+t)
        int col = n0 + wn * 64 + n * 16 + lr;           // feature
        int b = row >> 11, t = row & (N_T - 1);
        int hh = col >> 6, dh = col & 63;
        unsigned short val = f2bf(acc[m][n][r] * osc);
        if (z < 2)
          O[(((size_t)(b * N_H + hh)) * N_T + t) * N_DH + dh] = val;
        else
          O[(((size_t)(b * N_H + hh)) * N_DH + dh) * N_T + t] = val;
      }
}

// ------------------------------------------------------ output projection GEMM
__launch_bounds__(256, 2)
__global__ void proj_out(const unsigned short* __restrict__ A,
                         const unsigned short* __restrict__ W,
                         float* __restrict__ out) {
  __shared__ unsigned short lds_a[128 * 64];
  __shared__ unsigned short lds_b[128 * 64];

  const int tid = threadIdx.x;
  const int wave = tid >> 6, lane = tid & 63;
  const int wm = wave >> 1, wn = wave & 1;
  const int lr = lane & 15, lg = lane >> 4;
  const int orig = blockIdx.y * 8 + blockIdx.x;
  const int swz = (orig & 7) * 64 + (orig >> 3);
  const int m0 = (swz >> 3) * 128, n0 = (swz & 7) * 128;
  const int sw = (lr & 7) << 4;

  f32x4 acc[4][4] = {};

  for (int k0 = 0; k0 < N_D; k0 += 64) {
    __syncthreads();
#pragma unroll
    for (int it = 0; it < 4; ++it) {
      int c = it * 256 + tid;
      int row = c >> 3;
      int sb = ((c & 7) * 16) ^ ((row & 7) << 4);
      gll16(&A[(size_t)(m0 + row) * N_D + k0 + (sb >> 1)], &lds_a[c * 8]);
      gll16(&W[(size_t)(n0 + row) * N_D + k0 + (sb >> 1)], &lds_b[c * 8]);
    }
    __syncthreads();

#pragma unroll
    for (int kk = 0; kk < 2; ++kk) {
      bf16x8 af[4], bfr[4];
      const int cb = (lg * 16 + kk * 64);
#pragma unroll
      for (int m = 0; m < 4; ++m)
        af[m] = *(bf16x8*)&lds_a[(wm * 64 + m * 16 + lr) * 64 + ((cb ^ sw) >> 1)];
#pragma unroll
      for (int n = 0; n < 4; ++n)
        bfr[n] = *(bf16x8*)&lds_b[(wn * 64 + n * 16 + lr) * 64 + ((cb ^ sw) >> 1)];
#pragma unroll
      for (int m = 0; m < 4; ++m)
#pragma unroll
        for (int n = 0; n < 4; ++n)
          acc[m][n] = __builtin_amdgcn_mfma_f32_16x16x32_bf16(af[m], bfr[n], acc[m][n], 0, 0, 0);
    }
  }

#pragma unroll
  for (int m = 0; m < 4; ++m)
#pragma unroll
    for (int n = 0; n < 4; ++n)
#pragma unroll
      for (int r = 0; r < 4; ++r) {
        int row = m0 + wm * 64 + m * 16 + lg * 4 + r;
        int col = n0 + wn * 64 + n * 16 + lr;
        out[(size_t)row * N_D + col] = acc[m][n][r];
      }
}

// ----------------------------------------------------------- flash attention
// KV-SPLIT: 1024 blocks (4 waves x 128 q-rows). Block = (bh, px, kh): q-tile
// pair {15-px, px}, processing key-half kh of each tile's range -> uniform
// 17 k-tiles/block, 4 blocks/CU (2x occupancy vs r14). XCD grouping: same-bh
// blocks share L%8. Partials: normalized O (bf16) + m,l (f32); merged by
// combine(). Per-tile body identical to r14 (verified): swapped-QK
// mfma_32x32x16, tile-level lane-local softmax (defer-max THR=8, base-2),
// P->bf16 via v_cvt_pk + permlane32_swap, l via mfma(P, ones).
__launch_bounds__(256, 4)
__global__ void attn(const unsigned short* __restrict__ qh,
                     const unsigned short* __restrict__ kh_,
                     const unsigned short* __restrict__ vt,
                     unsigned short* __restrict__ oP0,
                     unsigned short* __restrict__ oP1,
                     float* __restrict__ mlP) {
  __shared__ unsigned short k_lds[2][64 * 64];   // [key][d], XOR-swizzled
  __shared__ unsigned short v_lds[2][64 * 64];   // [d][key], XOR-swizzled

  const int tid = threadIdx.x;
  const int wave = tid >> 6, lane = tid & 63;
  const int l31 = lane & 31, hi = lane >> 5;
  // decode: L = bx + 16*by; same-bh blocks share L%8 (-> same XCD L2)
  const int L = (int)blockIdx.x + (int)blockIdx.y * 16;
  const int bh = (L & 7) | (((L >> 3) & 7) << 3);
  const int top = L >> 6;                        // 0..15
  const int px = top >> 1;                       // 0..7
  const int khalf = top & 1;                     // key half 0/1
  const size_t base = (size_t)bh * N_T * N_DH;
  const unsigned short* Q = qh + base;
  const unsigned short* K = kh_ + base;
  const unsigned short* V = vt + base;           // [DH][T]
  const int swr = (l31 & 7) << 4;                // frag-read swizzle (bytes)

  bf16x8 ones;
#pragma unroll
  for (int j = 0; j < 8; ++j) ones[j] = (short)0x3F80;   // 1.0 bf16

  auto stage = [&](int buf, int kb2) {
    const int kk0 = kb2 * 64;
#pragma unroll
    for (int it = 0; it < 2; ++it) {
      int c = it * 256 + tid;
      int row = c >> 3;
      int sb = ((c & 7) * 16) ^ ((row & 7) << 4);
      gll16(&K[(size_t)(kk0 + row) * N_DH + (sb >> 1)], &k_lds[buf][c * 8]);
      gll16(&V[(size_t)row * N_T + kk0 + (sb >> 1)], &v_lds[buf][c * 8]);
    }
  };

  for (int pass = 0; pass < 2; ++pass) {
    const int qt = pass ? px : (15 - px);
    const int s0 = khalf * (qt + 1);             // this block's k-tile range
    const int s1 = s0 + (qt + 1);
    const int q0w = qt * 128 + wave * 32;        // this wave's rows

    // Q frags (B-operand): lane holds Q[q0w+l31][i*16+hi*8 .. +7]
    bf16x8 qf[4];
#pragma unroll
    for (int i = 0; i < 4; ++i)
      qf[i] = *(const bf16x8*)&Q[(size_t)(q0w + l31) * N_DH + i * 16 + hi * 8];

    float m_r = -1e30f;
    f32x16 l_acc = {};                           // row-sums, o-register layout
    f32x16 o0 = {}, o1 = {};                     // dv 0-31 / 32-63

    __syncthreads();                             // prev pass fully consumed
    stage(0, s0);

    for (int kb = s0; kb < s1; ++kb) {
      const int cur = (kb - s0) & 1;
      __syncthreads();               // own vmcnt drained -> buf[cur] ready
      if (kb + 1 < s1) stage(cur ^ 1, kb + 1);

      const unsigned short* kt_ = k_lds[cur];
      const unsigned short* vt_ = v_lds[cur];

      const int kgb0 = kb * 64;                  // subblock key bases
      const int kgb1 = kb * 64 + 32;
      if (kgb0 > q0w + 31) continue;             // tile fully masked (uniform)
      const bool a1 = (kgb1 <= q0w + 31);

      // S^T = K @ Q^T for both subblocks (independent MFMA chains)
      f32x16 s0v = {}, s1v = {};
      __builtin_amdgcn_s_setprio(1);
#pragma unroll
      for (int i = 0; i < 4; ++i) {
        bf16x8 kf = *(const bf16x8*)&kt_[l31 * 64 + (((i * 32 + hi * 16) ^ swr) >> 1)];
        s0v = __builtin_amdgcn_mfma_f32_32x32x16_bf16(kf, qf[i], s0v, 0, 0, 0);
      }
      if (a1) {
#pragma unroll
        for (int i = 0; i < 4; ++i) {
          bf16x8 kf = *(const bf16x8*)&kt_[(32 + l31) * 64 + (((i * 32 + hi * 16) ^ swr) >> 1)];
          s1v = __builtin_amdgcn_mfma_f32_32x32x16_bf16(kf, qf[i], s1v, 0, 0, 0);
        }
      }
      __builtin_amdgcn_s_setprio(0);

      // causal mask: diagonal subblock(s) only
      if (kgb0 == q0w) {
#pragma unroll
        for (int j = 0; j < 16; ++j)
          if ((j & 3) + 8 * (j >> 2) + 4 * hi > l31) s0v[j] = -1e30f;
      }
      if (a1 && kgb1 == q0w) {
#pragma unroll
        for (int j = 0; j < 16; ++j)
          if ((j & 3) + 8 * (j >> 2) + 4 * hi > l31) s1v[j] = -1e30f;
      }

      // tile max (64 keys); cross-half via permlane32_swap (VALU, no DS)
      float mx = s0v[0];
#pragma unroll
      for (int j = 1; j < 16; ++j) mx = fmaxf(mx, s0v[j]);
      if (a1) {
#pragma unroll
        for (int j = 0; j < 16; ++j) mx = fmaxf(mx, s1v[j]);
      }
      {
        u32x2 rm = __builtin_amdgcn_permlane32_swap(
            __float_as_uint(mx), __float_as_uint(mx), false, false);
        mx = fmaxf(__uint_as_float(rm.x), __uint_as_float(rm.y));
      }
      if (__any(mx > m_r + 8.0f)) {
        float mn = fmaxf(m_r, mx);
        float al = exp2f(m_r - mn);
        m_r = mn;
#pragma unroll
        for (int j = 0; j < 16; ++j) {
          float aj = __shfl(al, (j & 3) + 8 * (j >> 2) + 4 * hi);
          o0[j] *= aj; o1[j] *= aj; l_acc[j] *= aj;
        }
      }

      // P = exp2(S - m), both subblocks
#pragma unroll
      for (int j = 0; j < 16; ++j) s0v[j] = exp2f(s0v[j] - m_r);
      if (a1) {
#pragma unroll
        for (int j = 0; j < 16; ++j) s1v[j] = exp2f(s1v[j] - m_r);
      }

      // subblock 0: P->bf16 A-frags via cvt_pk + permlane32_swap; PV
      {
        unsigned t01 = cvtpk_bf16(s0v[0], s0v[1]),   t45 = cvtpk_bf16(s0v[4], s0v[5]);
        unsigned t23 = cvtpk_bf16(s0v[2], s0v[3]),   t67 = cvtpk_bf16(s0v[6], s0v[7]);
        unsigned u01 = cvtpk_bf16(s0v[8], s0v[9]),   u45 = cvtpk_bf16(s0v[12], s0v[13]);
        unsigned u23 = cvtpk_bf16(s0v[10], s0v[11]), u67 = cvtpk_bf16(s0v[14], s0v[15]);
        u32x2 r0 = __builtin_amdgcn_permlane32_swap(t01, t45, false, false);
        u32x2 r1 = __builtin_amdgcn_permlane32_swap(t23, t67, false, false);
        u32x2 r2 = __builtin_amdgcn_permlane32_swap(u01, u45, false, false);
        u32x2 r3 = __builtin_amdgcn_permlane32_swap(u23, u67, false, false);
        union { unsigned u[4]; bf16x8 v; } pa0, pa1;
        pa0.u[0] = r0.x;  pa0.u[1] = r1.x;  pa0.u[2] = r0.y;  pa0.u[3] = r1.y;
        pa1.u[0] = r2.x;  pa1.u[1] = r3.x;  pa1.u[2] = r2.y;  pa1.u[3] = r3.y;

        const int c0 = ((hi * 16) ^ swr) >> 1;
        const int c1 = ((32 + hi * 16) ^ swr) >> 1;
        bf16x8 v00 = *(const bf16x8*)&vt_[l31 * 64 + c0];
        bf16x8 v01 = *(const bf16x8*)&vt_[(32 + l31) * 64 + c0];
        bf16x8 v10 = *(const bf16x8*)&vt_[l31 * 64 + c1];
        bf16x8 v11 = *(const bf16x8*)&vt_[(32 + l31) * 64 + c1];

        __builtin_amdgcn_s_setprio(1);
        o0 = __builtin_amdgcn_mfma_f32_32x32x16_bf16(pa0.v, v00, o0, 0, 0, 0);
        o1 = __builtin_amdgcn_mfma_f32_32x32x16_bf16(pa0.v, v01, o1, 0, 0, 0);
        o0 = __builtin_amdgcn_mfma_f32_32x32x16_bf16(pa1.v, v10, o0, 0, 0, 0);
        o1 = __builtin_amdgcn_mfma_f32_32x32x16_bf16(pa1.v, v11, o1, 0, 0, 0);
        l_acc = __builtin_amdgcn_mfma_f32_32x32x16_bf16(pa0.v, ones, l_acc, 0, 0, 0);
        l_acc = __builtin_amdgcn_mfma_f32_32x32x16_bf16(pa1.v, ones, l_acc, 0, 0, 0);
        __builtin_amdgcn_s_setprio(0);
      }

      // subblock 1
      if (a1) {
        unsigned t01 = cvtpk_bf16(s1v[0], s1v[1]),   t45 = cvtpk_bf16(s1v[4], s1v[5]);
        unsigned t23 = cvtpk_bf16(s1v[2], s1v[3]),   t67 = cvtpk_bf16(s1v[6], s1v[7]);
        unsigned u01 = cvtpk_bf16(s1v[8], s1v[9]),   u45 = cvtpk_bf16(s1v[12], s1v[13]);
        unsigned u23 = cvtpk_bf16(s1v[10], s1v[11]), u67 = cvtpk_bf16(s1v[14], s1v[15]);
        u32x2 r0 = __builtin_amdgcn_permlane32_swap(t01, t45, false, false);
        u32x2 r1 = __builtin_amdgcn_permlane32_swap(t23, t67, false, false);
        u32x2 r2 = __builtin_amdgcn_permlane32_swap(u01, u45, false, false);
        u32x2 r3 = __builtin_amdgcn_permlane32_swap(u23, u67, false, false);
        union { unsigned u[4]; bf16x8 v; } pb0, pb1;
        pb0.u[0] = r0.x;  pb0.u[1] = r1.x;  pb0.u[2] = r0.y;  pb0.u[3] = r1.y;
        pb1.u[0] = r2.x;  pb1.u[1] = r3.x;  pb1.u[2] = r2.y;  pb1.u[3] = r3.y;

        const int c0 = ((64 + hi * 16) ^ swr) >> 1;
        const int c1 = ((96 + hi * 16) ^ swr) >> 1;
        bf16x8 v00 = *(const bf16x8*)&vt_[l31 * 64 + c0];
        bf16x8 v01 = *(const bf16x8*)&vt_[(32 + l31) * 64 + c0];
        bf16x8 v10 = *(const bf16x8*)&vt_[l31 * 64 + c1];
        bf16x8 v11 = *(const bf16x8*)&vt_[(32 + l31) * 64 + c1];

        __builtin_amdgcn_s_setprio(1);
        o0 = __builtin_amdgcn_mfma_f32_32x32x16_bf16(pb0.v, v00, o0, 0, 0, 0);
        o1 = __builtin_amdgcn_mfma_f32_32x32x16_bf16(pb0.v, v01, o1, 0, 0, 0);
        o0 = __builtin_amdgcn_mfma_f32_32x32x16_bf16(pb1.v, v10, o0, 0, 0, 0);
        o1 = __builtin_amdgcn_mfma_f32_32x32x16_bf16(pb1.v, v11, o1, 0, 0, 0);
        l_acc = __builtin_amdgcn_mfma_f32_32x32x16_bf16(pb0.v, ones, l_acc, 0, 0, 0);
        l_acc = __builtin_amdgcn_mfma_f32_32x32x16_bf16(pb1.v, ones, l_acc, 0, 0, 0);
        __builtin_amdgcn_s_setprio(0);
      }
    }

    // epilogue: normalized partial O (bf16) + m,l (f32) sidecar
    unsigned short* oP = khalf ? oP1 : oP0;
    float* mP = mlP + khalf * (2 * N_ROWS);
    float* lP = mP + N_ROWS;
    const int row0 = bh * N_T + q0w;
#pragma unroll
    for (int j = 0; j < 16; ++j) {
      float lv = l_acc[j];
      float inv = lv > 0.f ? 1.0f / lv : 0.f;
      int ridx = (j & 3) + 8 * (j >> 2) + 4 * hi;
      size_t rb = (size_t)(row0 + ridx) * 64 + l31;
      oP[rb]      = f2bf(o0[j] * inv);
      oP[rb + 32] = f2bf(o1[j] * inv);
    }
    if (l31 == 0) {
#pragma unroll
      for (int j = 0; j < 16; ++j) {
        int ridx = (j & 3) + 8 * (j >> 2) + 4 * hi;
        lP[row0 + ridx] = l_acc[j];
      }
    }
    if (hi == 0) mP[row0 + l31] = m_r;
  }
}

// -------------------------------------------------- combine kv-split partials
__global__ void combine(const unsigned short* __restrict__ oP0,
                        const unsigned short* __restrict__ oP1,
                        const float* __restrict__ mlP,
                        unsigned short* __restrict__ att) {
  const int gid = blockIdx.x * 256 + threadIdx.x;
  const int row = gid >> 3;            // 0..131071 (bh*2048 + t)
  const int dv0 = (gid & 7) * 8;
  const float m1 = mlP[row],               l1 = mlP[N_ROWS + row];
  const float m2 = mlP[2 * N_ROWS + row],  l2 = mlP[3 * N_ROWS + row];
  const float mm = fmaxf(m1, m2);
  const float w1 = exp2f(m1 - mm) * l1;
  const float w2 = exp2f(m2 - mm) * l2;
  const float inv = 1.0f / (w1 + w2);
  const float c1 = w1 * inv, c2 = w2 * inv;
  bf16x8 a = *(const bf16x8*)&oP0[(size_t)row * 64 + dv0];
  bf16x8 bvv = *(const bf16x8*)&oP1[(size_t)row * 64 + dv0];
  const int bh = row >> 11, t = row & (N_T - 1);
  const int b = bh >> 4, h = bh & 15;
  unsigned short* dst = att + ((size_t)(b * N_T + t)) * N_D + h * 64 + dv0;
  bf16x8 r;
#pragma unroll
  for (int i = 0; i < 8; ++i) {
    float f1 = __uint_as_float(((unsigned)(unsigned short)a[i]) << 16);
    float f2 = __uint_as_float(((unsigned)(unsigned short)bvv[i]) << 16);
    r[i] = (short)f2bf(f1 * c1 + f2 * c2);
  }
  *(bf16x8*)dst = r;
}

// ---------------------------------------------------------------------- launch
extern "C" void kernel_launch(void* const* d_in, const int* in_sizes, int n_in,
                              void* d_out, int out_size, void* d_ws, size_t ws_size,
                              hipStream_t stream) {
  (void)in_sizes; (void)n_in; (void)out_size; (void)ws_size;
  const float* q  = (const float*)d_in[0];
  const float* k  = (const float*)d_in[1];
  const float* v  = (const float*)d_in[2];
  const float* wq = (const float*)d_in[3];
  const float* wk = (const float*)d_in[4];
  const float* wv = (const float*)d_in[5];
  const float* wo = (const float*)d_in[6];
  float* out = (float*)d_out;

  unsigned short* ws = (unsigned short*)d_ws;
  const size_t W_ELEMS = (size_t)N_D * N_D;           // 1M
  const size_t T_ELEMS = (size_t)N_B * N_T * N_D;     // 8M
  unsigned short* wqb = ws;                 // 4 weights
  unsigned short* wkb = wqb + W_ELEMS;
  unsigned short* wvb = wkb + W_ELEMS;
  unsigned short* wob = wvb + W_ELEMS;
  unsigned short* qb  = wob + W_ELEMS;      // bf16 inputs
  unsigned short* kb  = qb + T_ELEMS;
  unsigned short* vb  = kb + T_ELEMS;
  unsigned short* qhb = vb + T_ELEMS;
  unsigned short* khb = qhb + T_ELEMS;
  unsigned short* vtb = khb + T_ELEMS;
  unsigned short* att = qb;                 // alias: qb dead after proj_qkv
  unsigned short* oP0 = kb;                 // alias: kb dead after proj_qkv
  unsigned short* oP1 = vb;                 // alias: vb dead after proj_qkv
  float* mlP = (float*)(vtb + T_ELEMS);     // 4 * 131072 floats = 2 MB

  cast_all<<<dim3(4096, 1, 7), 256, 0, stream>>>(wq, wk, wv, wo, q, k, v, ws);
  proj_qkv<<<dim3(8, 64, 3), 256, 0, stream>>>(qb, kb, vb, wqb, wkb, wvb, qhb, khb, vtb);
  attn<<<dim3(16, 64), 256, 0, stream>>>(qhb, khb, vtb, oP0, oP1, mlP);
  combine<<<dim3(4096), 256, 0, stream>>>(oP0, oP1, mlP, att);
  proj_out<<<dim3(8, 64), 256, 0, stream>>>(att, wob, out);
}

// Round 16
// 183.312 us; speedup vs baseline: 1.2022x; 1.2022x over previous
//
#include <hip/hip_runtime.h>
#include <hip/hip_bf16.h>

typedef short bf16x8 __attribute__((ext_vector_type(8)));
typedef float f32x4 __attribute__((ext_vector_type(4)));
typedef float f32x16 __attribute__((ext_vector_type(16)));
typedef unsigned u32x2 __attribute__((ext_vector_type(2)));

#define N_B 4
#define N_T 2048
#define N_D 1024
#define N_H 16
#define N_DH 64

// 0.125 * log2(e): folds attention scale + exp->exp2 conversion into Q proj
#define Q_SCALE 0.18033688011112042f

__device__ __forceinline__ unsigned short f2bf(float f) {
  union { float f; unsigned int u; } c; c.f = f;
  unsigned int u = c.u;
  return (unsigned short)((u + 0x7FFFu + ((u >> 16) & 1u)) >> 16);
}

__device__ __forceinline__ unsigned cvtpk_bf16(float lo, float hi) {
  unsigned r;
  asm("v_cvt_pk_bf16_f32 %0, %1, %2" : "=v"(r) : "v"(lo), "v"(hi));
  return r;
}

// async global->LDS, 16B per lane (dest linear: wave base + lane*16)
__device__ __forceinline__ void gll16(const unsigned short* g, unsigned short* l) {
  __builtin_amdgcn_global_load_lds(
      (const __attribute__((address_space(1))) unsigned int*)(const void*)g,
      (__attribute__((address_space(3))) unsigned int*)(void*)l, 16, 0, 0);
}

// --------------------------------------------------- cast fp32 -> bf16 (weights)
__global__ void cast_w(const float* __restrict__ wq, const float* __restrict__ wk,
                       const float* __restrict__ wv, const float* __restrict__ wo,
                       unsigned short* __restrict__ ws) {
  const int z = blockIdx.z;
  const float* srcs[4] = {wq, wk, wv, wo};
  const float* src = srcs[z];
  unsigned short* d = ws + (size_t)z * (N_D * N_D);
  const int i = (blockIdx.x * 256 + threadIdx.x) * 8;
  float4 a = *(const float4*)(src + i);
  float4 b = *(const float4*)(src + i + 4);
  bf16x8 p;
  p[0] = (short)f2bf(a.x); p[1] = (short)f2bf(a.y);
  p[2] = (short)f2bf(a.z); p[3] = (short)f2bf(a.w);
  p[4] = (short)f2bf(b.x); p[5] = (short)f2bf(b.y);
  p[6] = (short)f2bf(b.z); p[7] = (short)f2bf(b.w);
  *(bf16x8*)(d + i) = p;
}

// --------------------------------------------------------- qkv projection GEMM
// y = x @ W.T. A = ORIGINAL fp32 inputs, reg-staged (float4x2 -> cvt_pk ->
// ds_write_b128) into the SAME swizzled bf16 LDS layout the gload_lds path
// used; B (bf16 weights) via global_load_lds (issued first, async).
// q output: [B,H,T,DH] scaled by Q_SCALE ; k: [B,H,T,DH] ; v: TRANSPOSED [B,H,DH,T].
__launch_bounds__(256, 2)
__global__ void proj_qkv(const float* __restrict__ qf32,
                         const float* __restrict__ kf32,
                         const float* __restrict__ vf32,
                         const unsigned short* __restrict__ wq,
                         const unsigned short* __restrict__ wk,
                         const unsigned short* __restrict__ wv,
                         unsigned short* __restrict__ qh,
                         unsigned short* __restrict__ kh,
                         unsigned short* __restrict__ vt) {
  const int z = blockIdx.z;
  const float* X = (z == 0) ? qf32 : (z == 1) ? kf32 : vf32;
  const unsigned short* W = (z == 0) ? wq : (z == 1) ? wk : wv;
  unsigned short* O = (z == 0) ? qh : (z == 1) ? kh : vt;

  __shared__ unsigned short lds_a[128 * 64];
  __shared__ unsigned short lds_b[128 * 64];

  const int tid = threadIdx.x;
  const int wave = tid >> 6, lane = tid & 63;
  const int wm = wave >> 1, wn = wave & 1;
  const int lr = lane & 15, lg = lane >> 4;
  const int orig = blockIdx.y * 8 + blockIdx.x;
  const int swz = (orig & 7) * 64 + (orig >> 3);
  const int m0 = (swz >> 3) * 128, n0 = (swz & 7) * 128;
  const int sw = (lr & 7) << 4;

  f32x4 acc[4][4] = {};

  for (int k0 = 0; k0 < N_D; k0 += 64) {
    __syncthreads();
    // B: async global->LDS (issued first so it flies under A's reg staging)
#pragma unroll
    for (int it = 0; it < 4; ++it) {
      int c = it * 256 + tid;
      int row = c >> 3;
      int sb = ((c & 7) * 16) ^ ((row & 7) << 4);
      gll16(&W[(size_t)(n0 + row) * N_D + k0 + (sb >> 1)], &lds_b[c * 8]);
    }
    // A: fp32 -> bf16 reg staging into the identical swizzled layout
#pragma unroll
    for (int it = 0; it < 4; ++it) {
      int c = it * 256 + tid;
      int row = c >> 3;
      int sb = ((c & 7) * 16) ^ ((row & 7) << 4);   // bf16-byte offset in row
      const float* src = &X[(size_t)(m0 + row) * N_D + k0 + (sb >> 1)];
      float4 f0 = ((const float4*)src)[0];
      float4 f1 = ((const float4*)src)[1];
      union { unsigned u[4]; bf16x8 v; } pk;
      pk.u[0] = cvtpk_bf16(f0.x, f0.y); pk.u[1] = cvtpk_bf16(f0.z, f0.w);
      pk.u[2] = cvtpk_bf16(f1.x, f1.y); pk.u[3] = cvtpk_bf16(f1.z, f1.w);
      *(bf16x8*)&lds_a[c * 8] = pk.v;
    }
    __syncthreads();

#pragma unroll
    for (int kk = 0; kk < 2; ++kk) {
      bf16x8 af[4], bfr[4];
      const int cb = (lg * 16 + kk * 64);
#pragma unroll
      for (int m = 0; m < 4; ++m)
        af[m] = *(bf16x8*)&lds_a[(wm * 64 + m * 16 + lr) * 64 + ((cb ^ sw) >> 1)];
#pragma unroll
      for (int n = 0; n < 4; ++n)
        bfr[n] = *(bf16x8*)&lds_b[(wn * 64 + n * 16 + lr) * 64 + ((cb ^ sw) >> 1)];
#pragma unroll
      for (int m = 0; m < 4; ++m)
#pragma unroll
        for (int n = 0; n < 4; ++n)
          acc[m][n] = __builtin_amdgcn_mfma_f32_16x16x32_bf16(af[m], bfr[n], acc[m][n], 0, 0, 0);
    }
  }

  const float osc = (z == 0) ? Q_SCALE : 1.0f;
#pragma unroll
  for (int m = 0; m < 4; ++m)
#pragma unroll
    for (int n = 0; n < 4; ++n)
#pragma unroll
      for (int r = 0; r < 4; ++r) {
        int row = m0 + wm * 64 + m * 16 + lg * 4 + r;   // token (b*T+t)
        int col = n0 + wn * 64 + n * 16 + lr;           // feature
        int b = row >> 11, t = row & (N_T - 1);
        int hh = col >> 6, dh = col & 63;
        unsigned short val = f2bf(acc[m][n][r] * osc);
        if (z < 2)
          O[(((size_t)(b * N_H + hh)) * N_T + t) * N_DH + dh] = val;
        else
          O[(((size_t)(b * N_H + hh)) * N_DH + dh) * N_T + t] = val;
      }
}

// ------------------------------------------------------ output projection GEMM
__launch_bounds__(256, 2)
__global__ void proj_out(const unsigned short* __restrict__ A,
                         const unsigned short* __restrict__ W,
                         float* __restrict__ out) {
  __shared__ unsigned short lds_a[128 * 64];
  __shared__ unsigned short lds_b[128 * 64];

  const int tid = threadIdx.x;
  const int wave = tid >> 6, lane = tid & 63;
  const int wm = wave >> 1, wn = wave & 1;
  const int lr = lane & 15, lg = lane >> 4;
  const int orig = blockIdx.y * 8 + blockIdx.x;
  const int swz = (orig & 7) * 64 + (orig >> 3);
  const int m0 = (swz >> 3) * 128, n0 = (swz & 7) * 128;
  const int sw = (lr & 7) << 4;

  f32x4 acc[4][4] = {};

  for (int k0 = 0; k0 < N_D; k0 += 64) {
    __syncthreads();
#pragma unroll
    for (int it = 0; it < 4; ++it) {
      int c = it * 256 + tid;
      int row = c >> 3;
      int sb = ((c & 7) * 16) ^ ((row & 7) << 4);
      gll16(&A[(size_t)(m0 + row) * N_D + k0 + (sb >> 1)], &lds_a[c * 8]);
      gll16(&W[(size_t)(n0 + row) * N_D + k0 + (sb >> 1)], &lds_b[c * 8]);
    }
    __syncthreads();

#pragma unroll
    for (int kk = 0; kk < 2; ++kk) {
      bf16x8 af[4], bfr[4];
      const int cb = (lg * 16 + kk * 64);
#pragma unroll
      for (int m = 0; m < 4; ++m)
        af[m] = *(bf16x8*)&lds_a[(wm * 64 + m * 16 + lr) * 64 + ((cb ^ sw) >> 1)];
#pragma unroll
      for (int n = 0; n < 4; ++n)
        bfr[n] = *(bf16x8*)&lds_b[(wn * 64 + n * 16 + lr) * 64 + ((cb ^ sw) >> 1)];
#pragma unroll
      for (int m = 0; m < 4; ++m)
#pragma unroll
        for (int n = 0; n < 4; ++n)
          acc[m][n] = __builtin_amdgcn_mfma_f32_16x16x32_bf16(af[m], bfr[n], acc[m][n], 0, 0, 0);
    }
  }

#pragma unroll
  for (int m = 0; m < 4; ++m)
#pragma unroll
    for (int n = 0; n < 4; ++n)
#pragma unroll
      for (int r = 0; r < 4; ++r) {
        int row = m0 + wm * 64 + m * 16 + lg * 4 + r;
        int col = n0 + wn * 64 + n * 16 + lr;
        out[(size_t)row * N_D + col] = acc[m][n][r];
      }
}

// ----------------------------------------------------------- flash attention
// r14 schedule (best measured 81.4us): 512 blocks (4 waves x 128 q-rows),
// sequential q-tile pair {px, 15-px} (uniform 34 k-tiles/block), XCD grouping
// (same-bh blocks share L%8 -> KV L2-resident). Per wave: swapped-QK
// mfma_32x32x16, tile-level lane-local softmax (defer-max THR=8, base-2),
// P->bf16 A-frags via v_cvt_pk + v_permlane32_swap (VALU cross-half, no DS),
// l via mfma(P, ones) on the MFMA pipe.
__launch_bounds__(256, 2)
__global__ void attn(const unsigned short* __restrict__ qh,
                     const unsigned short* __restrict__ kh,
                     const unsigned short* __restrict__ vt,
                     unsigned short* __restrict__ att) {
  __shared__ unsigned short k_lds[2][64 * 64];   // [key][d], XOR-swizzled
  __shared__ unsigned short v_lds[2][64 * 64];   // [d][key], XOR-swizzled

  const int tid = threadIdx.x;
  const int wave = tid >> 6, lane = tid & 63;
  const int l31 = lane & 31, hi = lane >> 5;
  // XCD-grouping decode: same-bh blocks share L%8 (-> same XCD L2)
  const int L = (int)blockIdx.x + (int)blockIdx.y * 8;
  const int bh = (L & 7) | ((L >> 6) << 3);
  const int px = (L >> 3) & 7;
  const size_t base = (size_t)bh * N_T * N_DH;
  const unsigned short* Q = qh + base;
  const unsigned short* K = kh + base;
  const unsigned short* V = vt + base;           // [DH][T]
  const int b = bh >> 4, h = bh & 15;
  const int swr = (l31 & 7) << 4;                // frag-read swizzle (bytes)

  bf16x8 ones;
#pragma unroll
  for (int j = 0; j < 8; ++j) ones[j] = (short)0x3F80;   // 1.0 bf16

  auto stage = [&](int buf, int kb2) {
    const int kk0 = kb2 * 64;
#pragma unroll
    for (int it = 0; it < 2; ++it) {
      int c = it * 256 + tid;
      int row = c >> 3;
      int sb = ((c & 7) * 16) ^ ((row & 7) << 4);
      gll16(&K[(size_t)(kk0 + row) * N_DH + (sb >> 1)], &k_lds[buf][c * 8]);
      gll16(&V[(size_t)row * N_T + kk0 + (sb >> 1)], &v_lds[buf][c * 8]);
    }
  };

  for (int half = 0; half < 2; ++half) {
    const int qt = half ? (15 - px) : px;
    const int q0w = qt * 128 + wave * 32;        // this wave's rows

    // Q frags (B-operand): lane holds Q[q0w+l31][i*16+hi*8 .. +7]
    bf16x8 qf[4];
#pragma unroll
    for (int i = 0; i < 4; ++i)
      qf[i] = *(const bf16x8*)&Q[(size_t)(q0w + l31) * N_DH + i * 16 + hi * 8];

    float m_r = -INFINITY;
    f32x16 l_acc = {};                           // row-sums, o-register layout
    f32x16 o0 = {}, o1 = {};                     // dv 0-31 / 32-63

    const int nkb = 2 * qt + 2;                  // 64-key LDS tiles

    __syncthreads();                             // prev half fully consumed
    stage(0, 0);

    for (int kb = 0; kb < nkb; ++kb) {
      const int cur = kb & 1;
      __syncthreads();               // own vmcnt drained -> buf[cur] ready
      if (kb + 1 < nkb) stage(cur ^ 1, kb + 1);

      const unsigned short* kt_ = k_lds[cur];
      const unsigned short* vt_ = v_lds[cur];

      const int kgb0 = kb * 64;                  // subblock key bases
      const int kgb1 = kb * 64 + 32;
      if (kgb0 > q0w + 31) continue;             // tile fully masked (uniform)
      const bool a1 = (kgb1 <= q0w + 31);

      // S^T = K @ Q^T for both subblocks (independent MFMA chains)
      f32x16 s0 = {}, s1 = {};
      __builtin_amdgcn_s_setprio(1);
#pragma unroll
      for (int i = 0; i < 4; ++i) {
        bf16x8 kf = *(const bf16x8*)&kt_[l31 * 64 + (((i * 32 + hi * 16) ^ swr) >> 1)];
        s0 = __builtin_amdgcn_mfma_f32_32x32x16_bf16(kf, qf[i], s0, 0, 0, 0);
      }
      if (a1) {
#pragma unroll
        for (int i = 0; i < 4; ++i) {
          bf16x8 kf = *(const bf16x8*)&kt_[(32 + l31) * 64 + (((i * 32 + hi * 16) ^ swr) >> 1)];
          s1 = __builtin_amdgcn_mfma_f32_32x32x16_bf16(kf, qf[i], s1, 0, 0, 0);
        }
      }
      __builtin_amdgcn_s_setprio(0);

      // causal mask: diagonal subblock(s) only
      if (kgb0 == q0w) {
#pragma unroll
        for (int j = 0; j < 16; ++j)
          if ((j & 3) + 8 * (j >> 2) + 4 * hi > l31) s0[j] = -1e30f;
      }
      if (a1 && kgb1 == q0w) {
#pragma unroll
        for (int j = 0; j < 16; ++j)
          if ((j & 3) + 8 * (j >> 2) + 4 * hi > l31) s1[j] = -1e30f;
      }

      // tile max (64 keys); cross-half via permlane32_swap (VALU, no DS)
      float mx = s0[0];
#pragma unroll
      for (int j = 1; j < 16; ++j) mx = fmaxf(mx, s0[j]);
      if (a1) {
#pragma unroll
        for (int j = 0; j < 16; ++j) mx = fmaxf(mx, s1[j]);
      }
      {
        u32x2 rm = __builtin_amdgcn_permlane32_swap(
            __float_as_uint(mx), __float_as_uint(mx), false, false);
        mx = fmaxf(__uint_as_float(rm.x), __uint_as_float(rm.y));
      }
      if (__any(mx > m_r + 8.0f)) {
        float mn = fmaxf(m_r, mx);
        float al = exp2f(m_r - mn);
        m_r = mn;
#pragma unroll
        for (int j = 0; j < 16; ++j) {
          float aj = __shfl(al, (j & 3) + 8 * (j >> 2) + 4 * hi);
          o0[j] *= aj; o1[j] *= aj; l_acc[j] *= aj;
        }
      }

      // P = exp2(S - m), both subblocks
#pragma unroll
      for (int j = 0; j < 16; ++j) s0[j] = exp2f(s0[j] - m_r);
      if (a1) {
#pragma unroll
        for (int j = 0; j < 16; ++j) s1[j] = exp2f(s1[j] - m_r);
      }

      // subblock 0: P->bf16 A-frags via cvt_pk + permlane32_swap; PV
      {
        unsigned t01 = cvtpk_bf16(s0[0], s0[1]),   t45 = cvtpk_bf16(s0[4], s0[5]);
        unsigned t23 = cvtpk_bf16(s0[2], s0[3]),   t67 = cvtpk_bf16(s0[6], s0[7]);
        unsigned u01 = cvtpk_bf16(s0[8], s0[9]),   u45 = cvtpk_bf16(s0[12], s0[13]);
        unsigned u23 = cvtpk_bf16(s0[10], s0[11]), u67 = cvtpk_bf16(s0[14], s0[15]);
        u32x2 r0 = __builtin_amdgcn_permlane32_swap(t01, t45, false, false);
        u32x2 r1 = __builtin_amdgcn_permlane32_swap(t23, t67, false, false);
        u32x2 r2 = __builtin_amdgcn_permlane32_swap(u01, u45, false, false);
        u32x2 r3 = __builtin_amdgcn_permlane32_swap(u23, u67, false, false);
        union { unsigned u[4]; bf16x8 v; } pa0, pa1;
        pa0.u[0] = r0.x;  pa0.u[1] = r1.x;  pa0.u[2] = r0.y;  pa0.u[3] = r1.y;
        pa1.u[0] = r2.x;  pa1.u[1] = r3.x;  pa1.u[2] = r2.y;  pa1.u[3] = r3.y;

        const int c0 = ((hi * 16) ^ swr) >> 1;
        const int c1 = ((32 + hi * 16) ^ swr) >> 1;
        bf16x8 v00 = *(const bf16x8*)&vt_[l31 * 64 + c0];
        bf16x8 v01 = *(const bf16x8*)&vt_[(32 + l31) * 64 + c0];
        bf16x8 v10 = *(const bf16x8*)&vt_[l31 * 64 + c1];
        bf16x8 v11 = *(const bf16x8*)&vt_[(32 + l31) * 64 + c1];

        __builtin_amdgcn_s_setprio(1);
        o0 = __builtin_amdgcn_mfma_f32_32x32x16_bf16(pa0.v, v00, o0, 0, 0, 0);
        o1 = __builtin_amdgcn_mfma_f32_32x32x16_bf16(pa0.v, v01, o1, 0, 0, 0);
        o0 = __builtin_amdgcn_mfma_f32_32x32x16_bf16(pa1.v, v10, o0, 0, 0, 0);
        o1 = __builtin_amdgcn_mfma_f32_32x32x16_bf16(pa1.v, v11, o1, 0, 0, 0);
        l_acc = __builtin_amdgcn_mfma_f32_32x32x16_bf16(pa0.v, ones, l_acc, 0, 0, 0);
        l_acc = __builtin_amdgcn_mfma_f32_32x32x16_bf16(pa1.v, ones, l_acc, 0, 0, 0);
        __builtin_amdgcn_s_setprio(0);
      }

      // subblock 1
      if (a1) {
        unsigned t01 = cvtpk_bf16(s1[0], s1[1]),   t45 = cvtpk_bf16(s1[4], s1[5]);
        unsigned t23 = cvtpk_bf16(s1[2], s1[3]),   t67 = cvtpk_bf16(s1[6], s1[7]);
        unsigned u01 = cvtpk_bf16(s1[8], s1[9]),   u45 = cvtpk_bf16(s1[12], s1[13]);
        unsigned u23 = cvtpk_bf16(s1[10], s1[11]), u67 = cvtpk_bf16(s1[14], s1[15]);
        u32x2 r0 = __builtin_amdgcn_permlane32_swap(t01, t45, false, false);
        u32x2 r1 = __builtin_amdgcn_permlane32_swap(t23, t67, false, false);
        u32x2 r2 = __builtin_amdgcn_permlane32_swap(u01, u45, false, false);
        u32x2 r3 = __builtin_amdgcn_permlane32_swap(u23, u67, false, false);
        union { unsigned u[4]; bf16x8 v; } pb0, pb1;
        pb0.u[0] = r0.x;  pb0.u[1] = r1.x;  pb0.u[2] = r0.y;  pb0.u[3] = r1.y;
        pb1.u[0] = r2.x;  pb1.u[1] = r3.x;  pb1.u[2] = r2.y;  pb1.u[3] = r3.y;

        const int c0 = ((64 + hi * 16) ^ swr) >> 1;
        const int c1 = ((96 + hi * 16) ^ swr) >> 1;
        bf16x8 v00 = *(const bf16x8*)&vt_[l31 * 64 + c0];
        bf16x8 v01 = *(const bf16x8*)&vt_[(32 + l31) * 64 + c0];
        bf16x8 v10 = *(const bf16x8*)&vt_[l31 * 64 + c1];
        bf16x8 v11 = *(const bf16x8*)&vt_[(32 + l31) * 64 + c1];

        __builtin_amdgcn_s_setprio(1);
        o0 = __builtin_amdgcn_mfma_f32_32x32x16_bf16(pb0.v, v00, o0, 0, 0, 0);
        o1 = __builtin_amdgcn_mfma_f32_32x32x16_bf16(pb0.v, v01, o1, 0, 0, 0);
        o0 = __builtin_amdgcn_mfma_f32_32x32x16_bf16(pb1.v, v10, o0, 0, 0, 0);
        o1 = __builtin_amdgcn_mfma_f32_32x32x16_bf16(pb1.v, v11, o1, 0, 0, 0);
        l_acc = __builtin_amdgcn_mfma_f32_32x32x16_bf16(pb0.v, ones, l_acc, 0, 0, 0);
        l_acc = __builtin_amdgcn_mfma_f32_32x32x16_bf16(pb1.v, ones, l_acc, 0, 0, 0);
        __builtin_amdgcn_s_setprio(0);
      }
    }

    // epilogue: att[b, t, h*64+dv]
#pragma unroll
    for (int j = 0; j < 16; ++j) {
      float inv = 1.0f / l_acc[j];
      int t = q0w + (j & 3) + 8 * (j >> 2) + 4 * hi;
      size_t rowb = ((size_t)(b * N_T + t)) * N_D + h * 64 + l31;
      att[rowb]      = f2bf(o0[j] * inv);
      att[rowb + 32] = f2bf(o1[j] * inv);
    }
  }
}

// ---------------------------------------------------------------------- launch
extern "C" void kernel_launch(void* const* d_in, const int* in_sizes, int n_in,
                              void* d_out, int out_size, void* d_ws, size_t ws_size,
                              hipStream_t stream) {
  (void)in_sizes; (void)n_in; (void)out_size; (void)ws_size;
  const float* q  = (const float*)d_in[0];
  const float* k  = (const float*)d_in[1];
  const float* v  = (const float*)d_in[2];
  const float* wq = (const float*)d_in[3];
  const float* wk = (const float*)d_in[4];
  const float* wv = (const float*)d_in[5];
  const float* wo = (const float*)d_in[6];
  float* out = (float*)d_out;

  unsigned short* ws = (unsigned short*)d_ws;
  const size_t W_ELEMS = (size_t)N_D * N_D;           // 1M
  const size_t T_ELEMS = (size_t)N_B * N_T * N_D;     // 8M
  unsigned short* wqb = ws;                 // 4 weights (bf16)
  unsigned short* wkb = wqb + W_ELEMS;
  unsigned short* wvb = wkb + W_ELEMS;
  unsigned short* wob = wvb + W_ELEMS;
  unsigned short* qhb = wob + W_ELEMS;      // per-head q/k/v^T
  unsigned short* khb = qhb + T_ELEMS;
  unsigned short* vtb = khb + T_ELEMS;
  unsigned short* att = vtb + T_ELEMS;

  cast_w<<<dim3(512, 1, 4), 256, 0, stream>>>(wq, wk, wv, wo, ws);
  proj_qkv<<<dim3(8, 64, 3), 256, 0, stream>>>(q, k, v, wqb, wkb, wvb, qhb, khb, vtb);
  attn<<<dim3(8, N_B * N_H), 256, 0, stream>>>(qhb, khb, vtb, att);
  proj_out<<<dim3(8, 64), 256, 0, stream>>>(att, wob, out);
}